// Round 8
// baseline (255.653 us; speedup 1.0000x reference)
//
#include <hip/hip_runtime.h>

#define N 8192
#define M 4
#define L 256

// ws layout (float offsets)
#define WS_SE   0              // [5][N] rank-scattered exp(hazard) — bijective plain stores
#define WS_RANK (5 * N)        // [N]    int ranks (strict-less count)
#define WS_KM   (6 * N)        // [0,2048) modality KL partials, [2048,4096) joint

#define RNKBLK 256             // rank blocks: 2 elems/thread, 16 lanes (subs) per elem-pair
#define KLB 2048               // KL streaming blocks
#define GRID_A (RNKBLK + KLB)  // 2304; rank = bid%9==0 (exactly 256)

__device__ __forceinline__ float waveSum(float v) {
#pragma unroll
    for (int off = 32; off > 0; off >>= 1) v += __shfl_down(v, off, 64);
    return v;
}

__device__ __forceinline__ float kl4(float4 l, float4 s) {
    float k;
    k  = 0.5f * (s.x * s.x + l.x * l.x) - __logf(s.x) - 0.5f;
    k += 0.5f * (s.y * s.y + l.y * l.y) - __logf(s.y) - 0.5f;
    k += 0.5f * (s.z * s.z + l.z * l.z) - __logf(s.z) - 0.5f;
    k += 0.5f * (s.w * s.w + l.w * l.w) - __logf(s.w) - 0.5f;
    return k;
}

// ---- kernel A: rank+scatter (256 blocks) ∥ ALL KL streaming (2048 blocks) ----
__global__ __launch_bounds__(256) void kernelA(
    const float* __restrict__ jlh, const float* __restrict__ mlh,
    const float4* __restrict__ jloc4, const float4* __restrict__ jscale4,
    const float4* __restrict__ mloc4, const float4* __restrict__ mscale4,
    const float* __restrict__ target, float* __restrict__ ws)
{
    __shared__ float red[8];
    const int tid = threadIdx.x, bid = blockIdx.x;
    const float4* __restrict__ tg4 = (const float4*)target;   // {t,ev,t,ev} pairs

    if (bid % 9 == 0) {
        // ================= rank + scatter =================
        // thread owns elements e0=2p, e1=2p+1 (times in registers) and scans
        // table chunk `sub` (256 f4 = 1/16 of table). 8 compare-adds per load.
        const int gid  = (bid / 9) * 256 + tid;   // [0, 65536)
        const int pair = gid >> 4;                // [0, 4096)
        const int sub  = gid & 15;
        const float4 tp = tg4[pair];
        const float t0 = tp.x, t1 = tp.z;
        const int e0 = 2 * pair, e1 = 2 * pair + 1;
        const int base = sub * 256;

        int lt0 = 0, lt1 = 0, eq0 = 0, eq1 = 0;
#pragma unroll 4
        for (int k = 0; k < 256; k += 2) {        // 2 loads in flight per iter
            const float4 fa = tg4[base + k];
            const float4 fb = tg4[base + k + 1];
            lt0 += (fa.x <  t0) ? 1 : 0;  lt0 += (fa.z <  t0) ? 1 : 0;
            lt1 += (fa.x <  t1) ? 1 : 0;  lt1 += (fa.z <  t1) ? 1 : 0;
            eq0 += (fa.x == t0) ? 1 : 0;  eq0 += (fa.z == t0) ? 1 : 0;
            eq1 += (fa.x == t1) ? 1 : 0;  eq1 += (fa.z == t1) ? 1 : 0;
            lt0 += (fb.x <  t0) ? 1 : 0;  lt0 += (fb.z <  t0) ? 1 : 0;
            lt1 += (fb.x <  t1) ? 1 : 0;  lt1 += (fb.z <  t1) ? 1 : 0;
            eq0 += (fb.x == t0) ? 1 : 0;  eq0 += (fb.z == t0) ? 1 : 0;
            eq1 += (fb.x == t1) ? 1 : 0;  eq1 += (fb.z == t1) ? 1 : 0;
        }
        // combine the 16 subs (lanes [16k,16k+16) — masks 1,2,4,8 stay inside)
#pragma unroll
        for (int m = 1; m <= 8; m <<= 1) {
            lt0 += __shfl_xor(lt0, m, 64);
            lt1 += __shfl_xor(lt1, m, 64);
            eq0 += __shfl_xor(eq0, m, 64);
            eq1 += __shfl_xor(eq1, m, 64);
        }

        int slot0 = lt0, slot1 = lt1;             // unique when no ties (eq counts self)
        if (eq0 > 1 || eq1 > 1) {                 // rare, group-uniform: stable tie-break
            int q0 = 0, q1 = 0;
            for (int k = 0; k < 256; ++k) {
                const float4 f = tg4[base + k];
                const int j = (base + k) * 2;
                q0 += (f.x == t0 && j     < e0) ? 1 : 0;
                q0 += (f.z == t0 && j + 1 < e0) ? 1 : 0;
                q1 += (f.x == t1 && j     < e1) ? 1 : 0;
                q1 += (f.z == t1 && j + 1 < e1) ? 1 : 0;
            }
#pragma unroll
            for (int m = 1; m <= 8; m <<= 1) {
                q0 += __shfl_xor(q0, m, 64);
                q1 += __shfl_xor(q1, m, 64);
            }
            slot0 = lt0 + q0;
            slot1 = lt1 + q1;
        }

        if (sub == 0) {
            ((int*)ws)[WS_RANK + e0] = lt0;
            ((int*)ws)[WS_RANK + e1] = lt1;
        }
        if (sub < 5) {                            // scatter e0's 5 streams
            const float h = (sub == 0) ? jlh[e0] : mlh[(sub - 1) * N + e0];
            ws[WS_SE + sub * N + slot0] = __expf(h);
        } else if (sub < 10) {                    // scatter e1's 5 streams
            const int s = sub - 5;
            const float h = (s == 0) ? jlh[e1] : mlh[(s - 1) * N + e1];
            ws[WS_SE + s * N + slot1] = __expf(h);
        }
    } else {
        // ================= KL streaming (all 80 MB) =================
        const int kb = bid - bid / 9 - 1;         // 0..2047
        float km = 0.f, kj = 0.f;
#pragma unroll
        for (int it = 0; it < 4; ++it) {          // modality: 1024 f4-pairs/block
            const int idx = kb * 1024 + it * 256 + tid;
            km += kl4(mloc4[idx], mscale4[idx]);
        }
        {                                         // joint: 256 f4-pairs/block
            const int idx = kb * 256 + tid;
            kj += kl4(jloc4[idx], jscale4[idx]);
        }
        km = waveSum(km);
        kj = waveSum(kj);
        const int lane = tid & 63, w = tid >> 6;
        if (lane == 0) { red[w] = km; red[4 + w] = kj; }
        __syncthreads();
        if (tid == 0) ws[WS_KM + kb]        = red[0] + red[1] + red[2] + red[3];
        if (tid == 1) ws[WS_KM + 2048 + kb] = red[4] + red[5] + red[6] + red[7];
    }
}

// ---- kernel C: suffix-scan (in LDS) + gather + epilogue + combine ----
__global__ __launch_bounds__(1024) void kernelC(
    const float* __restrict__ jlh, const float* __restrict__ mlh,
    const float* __restrict__ target, const float* __restrict__ alpha_p,
    const float* __restrict__ beta_p, float* __restrict__ ws,
    float* __restrict__ out)
{
    __shared__ float suf[N];         // 32 KB suffix table for the current stream
    __shared__ float wt[16];
    __shared__ float red[16][8];

    const int tid = threadIdx.x;
    const int lane = tid & 63, w = tid >> 6;

    // per-thread metadata: 8 contiguous elements
    int   rk[8];
    float ev[8];
#pragma unroll
    for (int k = 0; k < 8; ++k) {
        const int i = tid * 8 + k;
        rk[k] = ((const int*)ws)[WS_RANK + i];
        ev[k] = target[2 * i + 1];
    }
    float evs = 0.f;
#pragma unroll
    for (int k = 0; k < 8; ++k) evs += ev[k];

    float c[5];
#pragma unroll
    for (int s = 0; s < 5; ++s) c[s] = 0.f;

    for (int s = 0; s < 5; ++s) {
        // load this stream's sortedE slice, local inclusive suffix over 8 elems
        const float4* __restrict__ src4 = (const float4*)(ws + WS_SE + s * N);
        const float4 a = src4[tid * 2], b = src4[tid * 2 + 1];
        float v[8];
        v[0] = a.x; v[1] = a.y; v[2] = a.z; v[3] = a.w;
        v[4] = b.x; v[5] = b.y; v[6] = b.z; v[7] = b.w;
#pragma unroll
        for (int k = 6; k >= 0; --k) v[k] += v[k + 1];
        const float T = v[0];
        // wave-level inclusive suffix of per-thread totals
        float x = T;
#pragma unroll
        for (int off = 1; off < 64; off <<= 1) {
            const float y = __shfl_down(x, off, 64);
            if (lane + off < 64) x += y;
        }
        __syncthreads();                 // all gathers of previous stream done
        if (lane == 0) wt[w] = x;        // wave totals
        __syncthreads();
        float offw = 0.f;
        for (int ww = w + 1; ww < 16; ++ww) offw += wt[ww];
        const float excl = offw + (x - T);   // strictly-later threads
#pragma unroll
        for (int k = 0; k < 8; ++k) suf[tid * 8 + k] = excl + v[k];
        __syncthreads();

        // gather + cox partial for this stream
        float cs = 0.f;
#pragma unroll
        for (int k = 0; k < 8; ++k) {
            const int i = tid * 8 + k;
            const float h = (s == 0) ? jlh[i] : mlh[(s - 1) * N + i];
            cs += ev[k] * (h - __logf(suf[rk[k]]));
        }
        c[s] = cs;
    }

    // KL partials: 2048 modality + 2048 joint, two each for tid<1024
    const float km = ws[WS_KM + tid] + ws[WS_KM + 1024 + tid];
    const float kj = ws[WS_KM + 2048 + tid] + ws[WS_KM + 3072 + tid];

    float vals[8] = {c[0], c[1], c[2], c[3], c[4], evs, km, kj};
#pragma unroll
    for (int q = 0; q < 8; ++q) {
        vals[q] = waveSum(vals[q]);
        if (lane == 0) red[w][q] = vals[q];
    }
    __syncthreads();
    if (tid == 0) {
        float t[8];
#pragma unroll
        for (int q = 0; q < 8; ++q) {
            float xx = 0.f;
            for (int ww = 0; ww < 16; ++ww) xx += red[ww][q];
            t[q] = xx;
        }
        const float EV = t[5];
        const float alpha = alpha_p[0], beta = beta_p[0];
        const float cox_j = -t[0] / EV;
        const float cox_m = -(t[1] + t[2] + t[3] + t[4]) / EV;
        out[0] = cox_j + beta * (t[7] / (float)N) + alpha * (cox_m + beta * (t[6] / (float)N));
    }
}

extern "C" void kernel_launch(void* const* d_in, const int* in_sizes, int n_in,
                              void* d_out, int out_size, void* d_ws, size_t ws_size,
                              hipStream_t stream) {
    const float* jlh    = (const float*)d_in[0];  // (N,)
    const float* mlh    = (const float*)d_in[1];  // (M,N)
    const float* jloc   = (const float*)d_in[2];  // (N,L)
    const float* jscale = (const float*)d_in[3];  // (N,L)
    const float* mloc   = (const float*)d_in[4];  // (M,N,L)
    const float* mscale = (const float*)d_in[5];  // (M,N,L)
    const float* target = (const float*)d_in[6];  // (N,2)
    const float* alpha  = (const float*)d_in[7];
    const float* beta   = (const float*)d_in[8];
    float* out = (float*)d_out;
    float* ws  = (float*)d_ws;

    kernelA<<<GRID_A, 256, 0, stream>>>(
        jlh, mlh, (const float4*)jloc, (const float4*)jscale,
        (const float4*)mloc, (const float4*)mscale, target, ws);
    kernelC<<<1, 1024, 0, stream>>>(jlh, mlh, target, alpha, beta, ws, out);
}

// Round 9
// 149.651 us; speedup vs baseline: 1.7083x; 1.7083x over previous
//
#include <hip/hip_runtime.h>

#define N 8192
#define M 4
#define L 256

// ws layout (float offsets)
#define WS_SE   0              // [5][N] rank-scattered exp(hazard) — bijective plain stores
#define WS_RANK (5 * N)        // [N]    int ranks (strict-less count)
#define WS_KM   (6 * N)        // [0,2048) modality KL partials, [2048,4096) joint

#define GRID_A 2048            // uniform blocks: KL chunk + 4-element rank chunk

__device__ __forceinline__ float waveSum(float v) {
#pragma unroll
    for (int off = 32; off > 0; off >>= 1) v += __shfl_down(v, off, 64);
    return v;
}

__device__ __forceinline__ int waveSumI(int v) {
#pragma unroll
    for (int off = 32; off > 0; off >>= 1) v += __shfl_down(v, off, 64);
    return v;
}

__device__ __forceinline__ float kl4(float4 l, float4 s) {
    float k;
    k  = 0.5f * (s.x * s.x + l.x * l.x) - __logf(s.x) - 0.5f;
    k += 0.5f * (s.y * s.y + l.y * l.y) - __logf(s.y) - 0.5f;
    k += 0.5f * (s.z * s.z + l.z * l.z) - __logf(s.z) - 0.5f;
    k += 0.5f * (s.w * s.w + l.w * l.w) - __logf(s.w) - 0.5f;
    return k;
}

// ---- kernel A: 2048 UNIFORM blocks. Phase 1: KL chunk. Phase 2: rank 4 elems. ----
__global__ __launch_bounds__(256) void kernelA(
    const float* __restrict__ jlh, const float* __restrict__ mlh,
    const float4* __restrict__ jloc4, const float4* __restrict__ jscale4,
    const float4* __restrict__ mloc4, const float4* __restrict__ mscale4,
    const float* __restrict__ target, float* __restrict__ ws)
{
    __shared__ float redK[8];        // KL cross-wave partials
    __shared__ int   redR[4][8];     // rank cross-wave: [wave][lt0..3, eq0..3]
    __shared__ int   tot[8];         // block totals: lt[4], eq[4]
    __shared__ int   tieoff[4];

    const int tid = threadIdx.x, bid = blockIdx.x;
    const int lane = tid & 63, w = tid >> 6;

    // ================= Phase 1: KL (all 10 loads issued up front) =================
    const int mb = bid * 1024 + tid;         // modality f4 base
    const int jb = bid * 256 + tid;          // joint f4
    float4 ml0 = mloc4[mb],       ms0 = mscale4[mb];
    float4 ml1 = mloc4[mb + 256], ms1 = mscale4[mb + 256];
    float4 ml2 = mloc4[mb + 512], ms2 = mscale4[mb + 512];
    float4 ml3 = mloc4[mb + 768], ms3 = mscale4[mb + 768];
    float4 jl  = jloc4[jb],       js  = jscale4[jb];

    float km = kl4(ml0, ms0) + kl4(ml1, ms1) + kl4(ml2, ms2) + kl4(ml3, ms3);
    float kj = kl4(jl, js);
    km = waveSum(km);
    kj = waveSum(kj);
    if (lane == 0) { redK[w] = km; redK[4 + w] = kj; }

    // ================= Phase 2: rank 4 elements =================
    const float4* __restrict__ tg4 = (const float4*)target;   // {t,ev,t,ev}
    const float4 tp0 = tg4[2 * bid], tp1 = tg4[2 * bid + 1];
    float te[4];
    te[0] = tp0.x; te[1] = tp0.z; te[2] = tp1.x; te[3] = tp1.z;

    int lt[4] = {0, 0, 0, 0}, eq[4] = {0, 0, 0, 0};

    // two batches of 8 forced-live float4 loads (coalesced, table read once/block)
    float4 buf[8];
#pragma unroll
    for (int k = 0; k < 8; ++k) buf[k] = tg4[tid + 256 * k];
#pragma unroll
    for (int k = 0; k < 8; ++k) {
        const float4 f = buf[k];
#pragma unroll
        for (int e = 0; e < 4; ++e) {
            lt[e] += (f.x <  te[e]) ? 1 : 0;
            lt[e] += (f.z <  te[e]) ? 1 : 0;
            eq[e] += (f.x == te[e]) ? 1 : 0;
            eq[e] += (f.z == te[e]) ? 1 : 0;
        }
    }
#pragma unroll
    for (int k = 0; k < 8; ++k) buf[k] = tg4[tid + 256 * (k + 8)];
#pragma unroll
    for (int k = 0; k < 8; ++k) {
        const float4 f = buf[k];
#pragma unroll
        for (int e = 0; e < 4; ++e) {
            lt[e] += (f.x <  te[e]) ? 1 : 0;
            lt[e] += (f.z <  te[e]) ? 1 : 0;
            eq[e] += (f.x == te[e]) ? 1 : 0;
            eq[e] += (f.z == te[e]) ? 1 : 0;
        }
    }

#pragma unroll
    for (int e = 0; e < 4; ++e) { lt[e] = waveSumI(lt[e]); eq[e] = waveSumI(eq[e]); }
    if (lane == 0) {
#pragma unroll
        for (int e = 0; e < 4; ++e) { redR[w][e] = lt[e]; redR[w][4 + e] = eq[e]; }
    }
    __syncthreads();

    if (tid < 8)  tot[tid] = redR[0][tid] + redR[1][tid] + redR[2][tid] + redR[3][tid];
    if (tid < 4)  tieoff[tid] = 0;
    if (tid == 8) ws[WS_KM + bid]        = redK[0] + redK[1] + redK[2] + redK[3];
    if (tid == 9) ws[WS_KM + 2048 + bid] = redK[4] + redK[5] + redK[6] + redK[7];
    __syncthreads();

    // rare, block-uniform tie handling: stable offset among equal times
    if (tot[4] > 1 || tot[5] > 1 || tot[6] > 1 || tot[7] > 1) {
        int ql[4] = {0, 0, 0, 0};
        for (int k = 0; k < 16; ++k) {
            const float4 f = tg4[tid + 256 * k];      // L2-hot rescan
            const int j = (tid + 256 * k) * 2;
#pragma unroll
            for (int e = 0; e < 4; ++e) {
                const int ee = bid * 4 + e;
                ql[e] += (f.x == te[e] && j     < ee) ? 1 : 0;
                ql[e] += (f.z == te[e] && j + 1 < ee) ? 1 : 0;
            }
        }
#pragma unroll
        for (int e = 0; e < 4; ++e) ql[e] = waveSumI(ql[e]);
        if (lane == 0) {
#pragma unroll
            for (int e = 0; e < 4; ++e) redR[w][e] = ql[e];
        }
        __syncthreads();
        if (tid < 4) tieoff[tid] = redR[0][tid] + redR[1][tid] + redR[2][tid] + redR[3][tid];
        __syncthreads();
    }

    // scatter: 20 plain stores (5 streams x 4 elems) + 4 rank stores
    if (tid < 20) {
        const int e = tid / 5, s = tid % 5;
        const int ee = bid * 4 + e;
        const int slot = tot[e] + tieoff[e];          // bijection 0..N-1 even with ties
        const float h = (s == 0) ? jlh[ee] : mlh[(s - 1) * N + ee];
        ws[WS_SE + s * N + slot] = __expf(h);
    } else if (tid < 24) {
        const int e = tid - 20;
        ((int*)ws)[WS_RANK + bid * 4 + e] = tot[e];
    }
}

// ---- kernel C: suffix-scan (in LDS) + gather + epilogue + combine ----
__global__ __launch_bounds__(1024) void kernelC(
    const float* __restrict__ jlh, const float* __restrict__ mlh,
    const float* __restrict__ target, const float* __restrict__ alpha_p,
    const float* __restrict__ beta_p, float* __restrict__ ws,
    float* __restrict__ out)
{
    __shared__ float suf[N];         // 32 KB suffix table for the current stream
    __shared__ float wt[16];
    __shared__ float red[16][8];

    const int tid = threadIdx.x;
    const int lane = tid & 63, w = tid >> 6;

    // per-thread metadata: 8 contiguous elements
    int   rk[8];
    float ev[8];
#pragma unroll
    for (int k = 0; k < 8; ++k) {
        const int i = tid * 8 + k;
        rk[k] = ((const int*)ws)[WS_RANK + i];
        ev[k] = target[2 * i + 1];
    }
    float evs = 0.f;
#pragma unroll
    for (int k = 0; k < 8; ++k) evs += ev[k];

    float c[5];
#pragma unroll
    for (int s = 0; s < 5; ++s) c[s] = 0.f;

    for (int s = 0; s < 5; ++s) {
        // load this stream's sortedE slice, local inclusive suffix over 8 elems
        const float4* __restrict__ src4 = (const float4*)(ws + WS_SE + s * N);
        const float4 a = src4[tid * 2], b = src4[tid * 2 + 1];
        float v[8];
        v[0] = a.x; v[1] = a.y; v[2] = a.z; v[3] = a.w;
        v[4] = b.x; v[5] = b.y; v[6] = b.z; v[7] = b.w;
#pragma unroll
        for (int k = 6; k >= 0; --k) v[k] += v[k + 1];
        const float T = v[0];
        // wave-level inclusive suffix of per-thread totals
        float x = T;
#pragma unroll
        for (int off = 1; off < 64; off <<= 1) {
            const float y = __shfl_down(x, off, 64);
            if (lane + off < 64) x += y;
        }
        __syncthreads();                 // all gathers of previous stream done
        if (lane == 0) wt[w] = x;        // wave totals
        __syncthreads();
        float offw = 0.f;
        for (int ww = w + 1; ww < 16; ++ww) offw += wt[ww];
        const float excl = offw + (x - T);   // strictly-later threads
#pragma unroll
        for (int k = 0; k < 8; ++k) suf[tid * 8 + k] = excl + v[k];
        __syncthreads();

        // gather + cox partial for this stream
        float cs = 0.f;
#pragma unroll
        for (int k = 0; k < 8; ++k) {
            const int i = tid * 8 + k;
            const float h = (s == 0) ? jlh[i] : mlh[(s - 1) * N + i];
            cs += ev[k] * (h - __logf(suf[rk[k]]));
        }
        c[s] = cs;
    }

    // KL partials: 2048 modality + 2048 joint, two each for tid<1024
    const float km = ws[WS_KM + tid] + ws[WS_KM + 1024 + tid];
    const float kj = ws[WS_KM + 2048 + tid] + ws[WS_KM + 3072 + tid];

    float vals[8] = {c[0], c[1], c[2], c[3], c[4], evs, km, kj};
#pragma unroll
    for (int q = 0; q < 8; ++q) {
        vals[q] = waveSum(vals[q]);
        if (lane == 0) red[w][q] = vals[q];
    }
    __syncthreads();
    if (tid == 0) {
        float t[8];
#pragma unroll
        for (int q = 0; q < 8; ++q) {
            float xx = 0.f;
            for (int ww = 0; ww < 16; ++ww) xx += red[ww][q];
            t[q] = xx;
        }
        const float EV = t[5];
        const float alpha = alpha_p[0], beta = beta_p[0];
        const float cox_j = -t[0] / EV;
        const float cox_m = -(t[1] + t[2] + t[3] + t[4]) / EV;
        out[0] = cox_j + beta * (t[7] / (float)N) + alpha * (cox_m + beta * (t[6] / (float)N));
    }
}

extern "C" void kernel_launch(void* const* d_in, const int* in_sizes, int n_in,
                              void* d_out, int out_size, void* d_ws, size_t ws_size,
                              hipStream_t stream) {
    const float* jlh    = (const float*)d_in[0];  // (N,)
    const float* mlh    = (const float*)d_in[1];  // (M,N)
    const float* jloc   = (const float*)d_in[2];  // (N,L)
    const float* jscale = (const float*)d_in[3];  // (N,L)
    const float* mloc   = (const float*)d_in[4];  // (M,N,L)
    const float* mscale = (const float*)d_in[5];  // (M,N,L)
    const float* target = (const float*)d_in[6];  // (N,2)
    const float* alpha  = (const float*)d_in[7];
    const float* beta   = (const float*)d_in[8];
    float* out = (float*)d_out;
    float* ws  = (float*)d_ws;

    kernelA<<<GRID_A, 256, 0, stream>>>(
        jlh, mlh, (const float4*)jloc, (const float4*)jscale,
        (const float4*)mloc, (const float4*)mscale, target, ws);
    kernelC<<<1, 1024, 0, stream>>>(jlh, mlh, target, alpha, beta, ws, out);
}

// Round 10
// 141.696 us; speedup vs baseline: 1.8042x; 1.0561x over previous
//
#include <hip/hip_runtime.h>

#define N 8192
#define M 4
#define L 256

// ws layout (float offsets)
#define WS_SE   0              // [5][N] rank-scattered exp(hazard) — bijective plain stores
#define WS_RANK (5 * N)        // [N]    int ranks (strict-less count)
#define WS_KM   (6 * N)        // [0,2048) modality KL partials, [2048,4096) joint
#define WS_FIN  (6 * N + 4096) // [0..4]=cox stream partials, [5]=event sum
#define WS_CNT  (6 * N + 4104) // int completion counter (init'd by kernelA)

#define GRID_A 2048            // uniform blocks: KL chunk + 4-element rank chunk

__device__ __forceinline__ float waveSum(float v) {
#pragma unroll
    for (int off = 32; off > 0; off >>= 1) v += __shfl_down(v, off, 64);
    return v;
}

__device__ __forceinline__ int waveSumI(int v) {
#pragma unroll
    for (int off = 32; off > 0; off >>= 1) v += __shfl_down(v, off, 64);
    return v;
}

__device__ __forceinline__ float kl4(float4 l, float4 s) {
    float k;
    k  = 0.5f * (s.x * s.x + l.x * l.x) - __logf(s.x) - 0.5f;
    k += 0.5f * (s.y * s.y + l.y * l.y) - __logf(s.y) - 0.5f;
    k += 0.5f * (s.z * s.z + l.z * l.z) - __logf(s.z) - 0.5f;
    k += 0.5f * (s.w * s.w + l.w * l.w) - __logf(s.w) - 0.5f;
    return k;
}

// ---- kernel A: 2048 UNIFORM blocks. Phase 1: KL chunk. Phase 2: rank 4 elems. ----
__global__ __launch_bounds__(256) void kernelA(
    const float* __restrict__ jlh, const float* __restrict__ mlh,
    const float4* __restrict__ jloc4, const float4* __restrict__ jscale4,
    const float4* __restrict__ mloc4, const float4* __restrict__ mscale4,
    const float* __restrict__ target, float* __restrict__ ws)
{
    __shared__ float redK[8];        // KL cross-wave partials
    __shared__ int   redR[4][8];     // rank cross-wave: [wave][lt0..3, eq0..3]
    __shared__ int   tot[8];         // block totals: lt[4], eq[4]
    __shared__ int   tieoff[4];

    const int tid = threadIdx.x, bid = blockIdx.x;
    const int lane = tid & 63, w = tid >> 6;

    if (bid == 0 && tid == 0) ((int*)ws)[WS_CNT] = 0;   // for kernelB's ticket

    // ================= Phase 1: KL (all 10 loads issued up front) =================
    const int mb = bid * 1024 + tid;         // modality f4 base
    const int jb = bid * 256 + tid;          // joint f4
    float4 ml0 = mloc4[mb],       ms0 = mscale4[mb];
    float4 ml1 = mloc4[mb + 256], ms1 = mscale4[mb + 256];
    float4 ml2 = mloc4[mb + 512], ms2 = mscale4[mb + 512];
    float4 ml3 = mloc4[mb + 768], ms3 = mscale4[mb + 768];
    float4 jl  = jloc4[jb],       js  = jscale4[jb];

    float km = kl4(ml0, ms0) + kl4(ml1, ms1) + kl4(ml2, ms2) + kl4(ml3, ms3);
    float kj = kl4(jl, js);
    km = waveSum(km);
    kj = waveSum(kj);
    if (lane == 0) { redK[w] = km; redK[4 + w] = kj; }

    // ================= Phase 2: rank 4 elements =================
    const float4* __restrict__ tg4 = (const float4*)target;   // {t,ev,t,ev}
    const float4 tp0 = tg4[2 * bid], tp1 = tg4[2 * bid + 1];
    float te[4];
    te[0] = tp0.x; te[1] = tp0.z; te[2] = tp1.x; te[3] = tp1.z;

    int lt[4] = {0, 0, 0, 0}, eq[4] = {0, 0, 0, 0};

    // two batches of 8 forced-live float4 loads (coalesced, table read once/block)
    float4 buf[8];
#pragma unroll
    for (int k = 0; k < 8; ++k) buf[k] = tg4[tid + 256 * k];
#pragma unroll
    for (int k = 0; k < 8; ++k) {
        const float4 f = buf[k];
#pragma unroll
        for (int e = 0; e < 4; ++e) {
            lt[e] += (f.x <  te[e]) ? 1 : 0;
            lt[e] += (f.z <  te[e]) ? 1 : 0;
            eq[e] += (f.x == te[e]) ? 1 : 0;
            eq[e] += (f.z == te[e]) ? 1 : 0;
        }
    }
#pragma unroll
    for (int k = 0; k < 8; ++k) buf[k] = tg4[tid + 256 * (k + 8)];
#pragma unroll
    for (int k = 0; k < 8; ++k) {
        const float4 f = buf[k];
#pragma unroll
        for (int e = 0; e < 4; ++e) {
            lt[e] += (f.x <  te[e]) ? 1 : 0;
            lt[e] += (f.z <  te[e]) ? 1 : 0;
            eq[e] += (f.x == te[e]) ? 1 : 0;
            eq[e] += (f.z == te[e]) ? 1 : 0;
        }
    }

#pragma unroll
    for (int e = 0; e < 4; ++e) { lt[e] = waveSumI(lt[e]); eq[e] = waveSumI(eq[e]); }
    if (lane == 0) {
#pragma unroll
        for (int e = 0; e < 4; ++e) { redR[w][e] = lt[e]; redR[w][4 + e] = eq[e]; }
    }
    __syncthreads();

    if (tid < 8)  tot[tid] = redR[0][tid] + redR[1][tid] + redR[2][tid] + redR[3][tid];
    if (tid < 4)  tieoff[tid] = 0;
    if (tid == 8) ws[WS_KM + bid]        = redK[0] + redK[1] + redK[2] + redK[3];
    if (tid == 9) ws[WS_KM + 2048 + bid] = redK[4] + redK[5] + redK[6] + redK[7];
    __syncthreads();

    // rare, block-uniform tie handling: stable offset among equal times
    if (tot[4] > 1 || tot[5] > 1 || tot[6] > 1 || tot[7] > 1) {
        int ql[4] = {0, 0, 0, 0};
        for (int k = 0; k < 16; ++k) {
            const float4 f = tg4[tid + 256 * k];      // L2-hot rescan
            const int j = (tid + 256 * k) * 2;
#pragma unroll
            for (int e = 0; e < 4; ++e) {
                const int ee = bid * 4 + e;
                ql[e] += (f.x == te[e] && j     < ee) ? 1 : 0;
                ql[e] += (f.z == te[e] && j + 1 < ee) ? 1 : 0;
            }
        }
#pragma unroll
        for (int e = 0; e < 4; ++e) ql[e] = waveSumI(ql[e]);
        if (lane == 0) {
#pragma unroll
            for (int e = 0; e < 4; ++e) redR[w][e] = ql[e];
        }
        __syncthreads();
        if (tid < 4) tieoff[tid] = redR[0][tid] + redR[1][tid] + redR[2][tid] + redR[3][tid];
        __syncthreads();
    }

    // scatter: 20 plain stores (5 streams x 4 elems) + 4 rank stores
    if (tid < 20) {
        const int e = tid / 5, s = tid % 5;
        const int ee = bid * 4 + e;
        const int slot = tot[e] + tieoff[e];          // bijection 0..N-1 even with ties
        const float h = (s == 0) ? jlh[ee] : mlh[(s - 1) * N + ee];
        ws[WS_SE + s * N + slot] = __expf(h);
    } else if (tid < 24) {
        const int e = tid - 20;
        ((int*)ws)[WS_RANK + bid * 4 + e] = tot[e];
    }
}

// ---- kernel B: 5 parallel stream blocks (scan + gather) + last-block combine ----
__global__ __launch_bounds__(1024) void kernelB(
    const float* __restrict__ jlh, const float* __restrict__ mlh,
    const float* __restrict__ target, const float* __restrict__ alpha_p,
    const float* __restrict__ beta_p, float* __restrict__ ws,
    float* __restrict__ out)
{
    __shared__ float suf[N];         // 32 KB suffix table for this block's stream
    __shared__ float wt[16];
    __shared__ float red[16][2];
    __shared__ int tk;

    const int tid = threadIdx.x, s = blockIdx.x;     // s = stream 0..4
    const int lane = tid & 63, w = tid >> 6;

    // ---- load this stream's sortedE slice + hierarchical suffix scan ----
    const float4* __restrict__ se4 = (const float4*)(ws + WS_SE + s * N);
    const float4 a = se4[tid * 2], b = se4[tid * 2 + 1];
    float v[8];
    v[0] = a.x; v[1] = a.y; v[2] = a.z; v[3] = a.w;
    v[4] = b.x; v[5] = b.y; v[6] = b.z; v[7] = b.w;
#pragma unroll
    for (int k = 6; k >= 0; --k) v[k] += v[k + 1];
    const float T = v[0];
    float x = T;                     // wave-level inclusive suffix of thread totals
#pragma unroll
    for (int off = 1; off < 64; off <<= 1) {
        const float y = __shfl_down(x, off, 64);
        if (lane + off < 64) x += y;
    }
    if (lane == 0) wt[w] = x;        // wave totals
    __syncthreads();
    float offw = 0.f;
    for (int ww = w + 1; ww < 16; ++ww) offw += wt[ww];
    const float excl = offw + (x - T);
#pragma unroll
    for (int k = 0; k < 8; ++k) suf[tid * 8 + k] = excl + v[k];
    __syncthreads();

    // ---- gather + cox partial for this stream (8 contiguous elements/thread) ----
    const float4* __restrict__ tg4 = (const float4*)target;
    const float4 p0 = tg4[tid * 4], p1 = tg4[tid * 4 + 1];
    const float4 p2 = tg4[tid * 4 + 2], p3 = tg4[tid * 4 + 3];
    const int4* __restrict__ rk4 = (const int4*)((const int*)ws + WS_RANK);
    const int4 r0 = rk4[tid * 2], r1 = rk4[tid * 2 + 1];
    const float4* __restrict__ hsrc =
        (s == 0) ? (const float4*)jlh : (const float4*)(mlh + (s - 1) * N);
    const float4 h0 = hsrc[tid * 2], h1 = hsrc[tid * 2 + 1];

    const float ev[8] = {p0.y, p0.w, p1.y, p1.w, p2.y, p2.w, p3.y, p3.w};
    const int   rk[8] = {r0.x, r0.y, r0.z, r0.w, r1.x, r1.y, r1.z, r1.w};
    const float hh[8] = {h0.x, h0.y, h0.z, h0.w, h1.x, h1.y, h1.z, h1.w};

    float cs = 0.f, evs = 0.f;
#pragma unroll
    for (int k = 0; k < 8; ++k) {
        cs += ev[k] * (hh[k] - __logf(suf[rk[k]]));
        evs += ev[k];
    }
    cs = waveSum(cs); evs = waveSum(evs);
    if (lane == 0) { red[w][0] = cs; red[w][1] = evs; }
    __syncthreads();

    if (tid == 0) {
        float c = 0.f, e = 0.f;
        for (int ww = 0; ww < 16; ++ww) { c += red[ww][0]; e += red[ww][1]; }
        __hip_atomic_store(&ws[WS_FIN + s], c, __ATOMIC_RELEASE, __HIP_MEMORY_SCOPE_AGENT);
        if (s == 0)
            __hip_atomic_store(&ws[WS_FIN + 5], e, __ATOMIC_RELEASE, __HIP_MEMORY_SCOPE_AGENT);
        tk = __hip_atomic_fetch_add((int*)ws + WS_CNT, 1,
                                    __ATOMIC_ACQ_REL, __HIP_MEMORY_SCOPE_AGENT);
    }
    __syncthreads();

    if (tk == 4) {                   // last-finishing block: combine everything
        float km = ws[WS_KM + tid] + ws[WS_KM + 1024 + tid];
        float kj = ws[WS_KM + 2048 + tid] + ws[WS_KM + 3072 + tid];
        km = waveSum(km); kj = waveSum(kj);
        if (lane == 0) { red[w][0] = km; red[w][1] = kj; }
        __syncthreads();
        if (tid == 0) {
            float tkm = 0.f, tkj = 0.f;
            for (int ww = 0; ww < 16; ++ww) { tkm += red[ww][0]; tkj += red[ww][1]; }
            float c[6];
#pragma unroll
            for (int q = 0; q < 6; ++q)
                c[q] = __hip_atomic_load(&ws[WS_FIN + q],
                                         __ATOMIC_RELAXED, __HIP_MEMORY_SCOPE_AGENT);
            const float EV = c[5];
            const float alpha = alpha_p[0], beta = beta_p[0];
            const float cox_j = -c[0] / EV;
            const float cox_m = -(c[1] + c[2] + c[3] + c[4]) / EV;
            out[0] = cox_j + beta * (tkj / (float)N) + alpha * (cox_m + beta * (tkm / (float)N));
        }
    }
}

extern "C" void kernel_launch(void* const* d_in, const int* in_sizes, int n_in,
                              void* d_out, int out_size, void* d_ws, size_t ws_size,
                              hipStream_t stream) {
    const float* jlh    = (const float*)d_in[0];  // (N,)
    const float* mlh    = (const float*)d_in[1];  // (M,N)
    const float* jloc   = (const float*)d_in[2];  // (N,L)
    const float* jscale = (const float*)d_in[3];  // (N,L)
    const float* mloc   = (const float*)d_in[4];  // (M,N,L)
    const float* mscale = (const float*)d_in[5];  // (M,N,L)
    const float* target = (const float*)d_in[6];  // (N,2)
    const float* alpha  = (const float*)d_in[7];
    const float* beta   = (const float*)d_in[8];
    float* out = (float*)d_out;
    float* ws  = (float*)d_ws;

    kernelA<<<GRID_A, 256, 0, stream>>>(
        jlh, mlh, (const float4*)jloc, (const float4*)jscale,
        (const float4*)mloc, (const float4*)mscale, target, ws);
    kernelB<<<5, 1024, 0, stream>>>(jlh, mlh, target, alpha, beta, ws, out);
}

// Round 11
// 139.873 us; speedup vs baseline: 1.8278x; 1.0130x over previous
//
#include <hip/hip_runtime.h>

#define N 8192
#define M 4
#define L 256

// ws layout (float offsets)
#define WS_SE   0              // [5][N] rank-scattered exp(hazard) — bijective plain stores
#define WS_RANK (5 * N)        // [N]    int ranks (strict-less count)
#define WS_KM   (6 * N)        // [0,2048) modality KL partials, [2048,4096) joint
#define WS_FIN  (6 * N + 4096) // [0..4]=cox, [5]=event sum, [6]=modKM, [7]=jointKM
#define WS_CNT  (6 * N + 4104) // int completion counter (init'd by kernelA)

#define GRID_A 2048            // uniform blocks: KL chunk + 4-element rank chunk

__device__ __forceinline__ float waveSum(float v) {
#pragma unroll
    for (int off = 32; off > 0; off >>= 1) v += __shfl_down(v, off, 64);
    return v;
}

__device__ __forceinline__ int waveSumI(int v) {
#pragma unroll
    for (int off = 32; off > 0; off >>= 1) v += __shfl_down(v, off, 64);
    return v;
}

__device__ __forceinline__ float kl4(float4 l, float4 s) {
    float k;
    k  = 0.5f * (s.x * s.x + l.x * l.x) - __logf(s.x) - 0.5f;
    k += 0.5f * (s.y * s.y + l.y * l.y) - __logf(s.y) - 0.5f;
    k += 0.5f * (s.z * s.z + l.z * l.z) - __logf(s.z) - 0.5f;
    k += 0.5f * (s.w * s.w + l.w * l.w) - __logf(s.w) - 0.5f;
    return k;
}

// ---- kernel A: 2048 UNIFORM blocks. KL chunk + rank 4 elems, loads issued early. ----
__global__ __launch_bounds__(256) void kernelA(
    const float* __restrict__ jlh, const float* __restrict__ mlh,
    const float4* __restrict__ jloc4, const float4* __restrict__ jscale4,
    const float4* __restrict__ mloc4, const float4* __restrict__ mscale4,
    const float* __restrict__ target, float* __restrict__ ws)
{
    __shared__ float redK[8];        // KL cross-wave partials
    __shared__ int   redR[4][8];     // rank cross-wave: [wave][lt0..3, eq0..3]
    __shared__ int   tot[8];         // block totals: lt[4], eq[4]
    __shared__ int   tieoff[4];

    const int tid = threadIdx.x, bid = blockIdx.x;
    const int lane = tid & 63, w = tid >> 6;

    if (bid == 0 && tid == 0) ((int*)ws)[WS_CNT] = 0;   // for kernelB's ticket

    const float4* __restrict__ tg4 = (const float4*)target;   // {t,ev,t,ev}

    // ---- issue ALL long-latency loads up front (T14 issue-early) ----
    const float4 tp0 = tg4[2 * bid], tp1 = tg4[2 * bid + 1];  // own times
    const int mb = bid * 1024 + tid;          // modality f4 base
    const int jb = bid * 256 + tid;           // joint f4
    float4 ml0 = mloc4[mb],       ms0 = mscale4[mb];
    float4 ml1 = mloc4[mb + 256], ms1 = mscale4[mb + 256];
    float4 ml2 = mloc4[mb + 512], ms2 = mscale4[mb + 512];
    float4 ml3 = mloc4[mb + 768], ms3 = mscale4[mb + 768];
    float4 jl  = jloc4[jb],       js  = jscale4[jb];

    const int st = bid & 15;                  // per-block stagger of table sweep
    float4 buf[8];
#pragma unroll
    for (int k = 0; k < 8; ++k) buf[k] = tg4[tid + 256 * ((k + st) & 15)];

    // ---- KL compute (table batch-1 still in flight underneath) ----
    float km = kl4(ml0, ms0) + kl4(ml1, ms1) + kl4(ml2, ms2) + kl4(ml3, ms3);
    float kj = kl4(jl, js);
    km = waveSum(km);
    kj = waveSum(kj);
    if (lane == 0) { redK[w] = km; redK[4 + w] = kj; }

    // ---- rank: batch-1 compares, issue batch-2, batch-2 compares ----
    float te[4];
    te[0] = tp0.x; te[1] = tp0.z; te[2] = tp1.x; te[3] = tp1.z;
    int lt[4] = {0, 0, 0, 0}, eq[4] = {0, 0, 0, 0};

#pragma unroll
    for (int k = 0; k < 8; ++k) {
        const float4 f = buf[k];
#pragma unroll
        for (int e = 0; e < 4; ++e) {
            lt[e] += (f.x <  te[e]) ? 1 : 0;
            lt[e] += (f.z <  te[e]) ? 1 : 0;
            eq[e] += (f.x == te[e]) ? 1 : 0;
            eq[e] += (f.z == te[e]) ? 1 : 0;
        }
    }
#pragma unroll
    for (int k = 0; k < 8; ++k) buf[k] = tg4[tid + 256 * ((k + 8 + st) & 15)];
#pragma unroll
    for (int k = 0; k < 8; ++k) {
        const float4 f = buf[k];
#pragma unroll
        for (int e = 0; e < 4; ++e) {
            lt[e] += (f.x <  te[e]) ? 1 : 0;
            lt[e] += (f.z <  te[e]) ? 1 : 0;
            eq[e] += (f.x == te[e]) ? 1 : 0;
            eq[e] += (f.z == te[e]) ? 1 : 0;
        }
    }

#pragma unroll
    for (int e = 0; e < 4; ++e) { lt[e] = waveSumI(lt[e]); eq[e] = waveSumI(eq[e]); }
    if (lane == 0) {
#pragma unroll
        for (int e = 0; e < 4; ++e) { redR[w][e] = lt[e]; redR[w][4 + e] = eq[e]; }
    }
    __syncthreads();

    if (tid < 8)  tot[tid] = redR[0][tid] + redR[1][tid] + redR[2][tid] + redR[3][tid];
    if (tid < 4)  tieoff[tid] = 0;
    if (tid == 8) ws[WS_KM + bid]        = redK[0] + redK[1] + redK[2] + redK[3];
    if (tid == 9) ws[WS_KM + 2048 + bid] = redK[4] + redK[5] + redK[6] + redK[7];
    __syncthreads();

    // rare, block-uniform tie handling: stable offset among equal times
    if (tot[4] > 1 || tot[5] > 1 || tot[6] > 1 || tot[7] > 1) {
        int ql[4] = {0, 0, 0, 0};
        for (int k = 0; k < 16; ++k) {
            const float4 f = tg4[tid + 256 * k];      // L2-hot rescan
            const int j = (tid + 256 * k) * 2;
#pragma unroll
            for (int e = 0; e < 4; ++e) {
                const int ee = bid * 4 + e;
                ql[e] += (f.x == te[e] && j     < ee) ? 1 : 0;
                ql[e] += (f.z == te[e] && j + 1 < ee) ? 1 : 0;
            }
        }
#pragma unroll
        for (int e = 0; e < 4; ++e) ql[e] = waveSumI(ql[e]);
        if (lane == 0) {
#pragma unroll
            for (int e = 0; e < 4; ++e) redR[w][e] = ql[e];
        }
        __syncthreads();
        if (tid < 4) tieoff[tid] = redR[0][tid] + redR[1][tid] + redR[2][tid] + redR[3][tid];
        __syncthreads();
    }

    // scatter: 20 plain stores (5 streams x 4 elems) + 4 rank stores
    if (tid < 20) {
        const int e = tid / 5, s = tid % 5;
        const int ee = bid * 4 + e;
        const int slot = tot[e] + tieoff[e];          // bijection 0..N-1 even with ties
        const float h = (s == 0) ? jlh[ee] : mlh[(s - 1) * N + ee];
        ws[WS_SE + s * N + slot] = __expf(h);
    } else if (tid < 24) {
        const int e = tid - 20;
        ((int*)ws)[WS_RANK + bid * 4 + e] = tot[e];
    }
}

// ---- kernel B: 5 parallel stream blocks (scan + gather + KM duty) + last-block combine ----
__global__ __launch_bounds__(1024) void kernelB(
    const float* __restrict__ jlh, const float* __restrict__ mlh,
    const float* __restrict__ target, const float* __restrict__ alpha_p,
    const float* __restrict__ beta_p, float* __restrict__ ws,
    float* __restrict__ out)
{
    __shared__ float suf[N];         // 32 KB suffix table for this block's stream
    __shared__ float wt[16];
    __shared__ float red[16][3];
    __shared__ int tk;

    const int tid = threadIdx.x, s = blockIdx.x;     // s = stream 0..4
    const int lane = tid & 63, w = tid >> 6;

    // ---- load this stream's sortedE slice + hierarchical suffix scan ----
    const float4* __restrict__ se4 = (const float4*)(ws + WS_SE + s * N);
    const float4 a = se4[tid * 2], b = se4[tid * 2 + 1];
    float v[8];
    v[0] = a.x; v[1] = a.y; v[2] = a.z; v[3] = a.w;
    v[4] = b.x; v[5] = b.y; v[6] = b.z; v[7] = b.w;
#pragma unroll
    for (int k = 6; k >= 0; --k) v[k] += v[k + 1];
    const float T = v[0];
    float x = T;                     // wave-level inclusive suffix of thread totals
#pragma unroll
    for (int off = 1; off < 64; off <<= 1) {
        const float y = __shfl_down(x, off, 64);
        if (lane + off < 64) x += y;
    }
    if (lane == 0) wt[w] = x;        // wave totals
    __syncthreads();
    float offw = 0.f;
    for (int ww = w + 1; ww < 16; ++ww) offw += wt[ww];
    const float excl = offw + (x - T);
#pragma unroll
    for (int k = 0; k < 8; ++k) suf[tid * 8 + k] = excl + v[k];
    __syncthreads();

    // ---- gather + cox partial for this stream (8 contiguous elements/thread) ----
    const float4* __restrict__ tg4 = (const float4*)target;
    const float4 p0 = tg4[tid * 4], p1 = tg4[tid * 4 + 1];
    const float4 p2 = tg4[tid * 4 + 2], p3 = tg4[tid * 4 + 3];
    const int4* __restrict__ rk4 = (const int4*)((const int*)ws + WS_RANK);
    const int4 r0 = rk4[tid * 2], r1 = rk4[tid * 2 + 1];
    const float4* __restrict__ hsrc =
        (s == 0) ? (const float4*)jlh : (const float4*)(mlh + (s - 1) * N);
    const float4 h0 = hsrc[tid * 2], h1 = hsrc[tid * 2 + 1];

    const float ev[8] = {p0.y, p0.w, p1.y, p1.w, p2.y, p2.w, p3.y, p3.w};
    const int   rk[8] = {r0.x, r0.y, r0.z, r0.w, r1.x, r1.y, r1.z, r1.w};
    const float hh[8] = {h0.x, h0.y, h0.z, h0.w, h1.x, h1.y, h1.z, h1.w};

    float cs = 0.f, evs = 0.f;
#pragma unroll
    for (int k = 0; k < 8; ++k) {
        cs += ev[k] * (hh[k] - __logf(suf[rk[k]]));
        evs += ev[k];
    }

    // ---- extra duty (parallel with other blocks): KM pre-combine ----
    float extra = 0.f;
    if (s == 1)      extra = ws[WS_KM + tid]        + ws[WS_KM + 1024 + tid];  // modality
    else if (s == 2) extra = ws[WS_KM + 2048 + tid] + ws[WS_KM + 3072 + tid];  // joint

    cs = waveSum(cs); evs = waveSum(evs); extra = waveSum(extra);
    if (lane == 0) { red[w][0] = cs; red[w][1] = evs; red[w][2] = extra; }
    __syncthreads();

    if (tid == 0) {
        float c = 0.f, e = 0.f, xx = 0.f;
        for (int ww = 0; ww < 16; ++ww) { c += red[ww][0]; e += red[ww][1]; xx += red[ww][2]; }
        __hip_atomic_store(&ws[WS_FIN + s], c, __ATOMIC_RELEASE, __HIP_MEMORY_SCOPE_AGENT);
        if (s == 0)
            __hip_atomic_store(&ws[WS_FIN + 5], e, __ATOMIC_RELEASE, __HIP_MEMORY_SCOPE_AGENT);
        if (s == 1)
            __hip_atomic_store(&ws[WS_FIN + 6], xx, __ATOMIC_RELEASE, __HIP_MEMORY_SCOPE_AGENT);
        if (s == 2)
            __hip_atomic_store(&ws[WS_FIN + 7], xx, __ATOMIC_RELEASE, __HIP_MEMORY_SCOPE_AGENT);
        tk = __hip_atomic_fetch_add((int*)ws + WS_CNT, 1,
                                    __ATOMIC_ACQ_REL, __HIP_MEMORY_SCOPE_AGENT);
    }
    __syncthreads();

    if (tk == 4 && tid == 0) {       // last-finishing block: 8 scalar loads + arithmetic
        float c[8];
#pragma unroll
        for (int q = 0; q < 8; ++q)
            c[q] = __hip_atomic_load(&ws[WS_FIN + q],
                                     __ATOMIC_RELAXED, __HIP_MEMORY_SCOPE_AGENT);
        const float EV = c[5];
        const float alpha = alpha_p[0], beta = beta_p[0];
        const float cox_j = -c[0] / EV;
        const float cox_m = -(c[1] + c[2] + c[3] + c[4]) / EV;
        out[0] = cox_j + beta * (c[7] / (float)N) + alpha * (cox_m + beta * (c[6] / (float)N));
    }
}

extern "C" void kernel_launch(void* const* d_in, const int* in_sizes, int n_in,
                              void* d_out, int out_size, void* d_ws, size_t ws_size,
                              hipStream_t stream) {
    const float* jlh    = (const float*)d_in[0];  // (N,)
    const float* mlh    = (const float*)d_in[1];  // (M,N)
    const float* jloc   = (const float*)d_in[2];  // (N,L)
    const float* jscale = (const float*)d_in[3];  // (N,L)
    const float* mloc   = (const float*)d_in[4];  // (M,N,L)
    const float* mscale = (const float*)d_in[5];  // (M,N,L)
    const float* target = (const float*)d_in[6];  // (N,2)
    const float* alpha  = (const float*)d_in[7];
    const float* beta   = (const float*)d_in[8];
    float* out = (float*)d_out;
    float* ws  = (float*)d_ws;

    kernelA<<<GRID_A, 256, 0, stream>>>(
        jlh, mlh, (const float4*)jloc, (const float4*)jscale,
        (const float4*)mloc, (const float4*)mscale, target, ws);
    kernelB<<<5, 1024, 0, stream>>>(jlh, mlh, target, alpha, beta, ws, out);
}

// Round 12
// 138.941 us; speedup vs baseline: 1.8400x; 1.0067x over previous
//
#include <hip/hip_runtime.h>

#define N 8192
#define M 4
#define L 256

// ws layout (float offsets)
#define WS_SE   0              // [5][N] rank-scattered exp(hazard) — bijective plain stores
#define WS_RANK (5 * N)        // [N]    int ranks (strict-less count)
#define WS_KM   (6 * N)        // [0,1024) modality KL partials, [1024,2048) joint
#define WS_FIN  (6 * N + 2048) // [0..4]=cox, [5]=event sum, [6]=modKM, [7]=jointKM
#define WS_CNT  (6 * N + 2056) // int completion counter (init'd by kernelA, used by B)

#define GRID_A 1024            // uniform worker blocks: KL chunk + 8-element rank chunk

__device__ __forceinline__ float waveSum(float v) {
#pragma unroll
    for (int off = 32; off > 0; off >>= 1) v += __shfl_down(v, off, 64);
    return v;
}

__device__ __forceinline__ int waveSumI(int v) {
#pragma unroll
    for (int off = 32; off > 0; off >>= 1) v += __shfl_down(v, off, 64);
    return v;
}

__device__ __forceinline__ float kl4(float4 l, float4 s) {
    float k;
    k  = 0.5f * (s.x * s.x + l.x * l.x) - __logf(s.x) - 0.5f;
    k += 0.5f * (s.y * s.y + l.y * l.y) - __logf(s.y) - 0.5f;
    k += 0.5f * (s.z * s.z + l.z * l.z) - __logf(s.z) - 0.5f;
    k += 0.5f * (s.w * s.w + l.w * l.w) - __logf(s.w) - 0.5f;
    return k;
}

// ---- kernel A: 1024 UNIFORM blocks. 20-deep KL load burst + rank 8 elems. ----
__global__ __launch_bounds__(256) void kernelA(
    const float* __restrict__ jlh, const float* __restrict__ mlh,
    const float4* __restrict__ jloc4, const float4* __restrict__ jscale4,
    const float4* __restrict__ mloc4, const float4* __restrict__ mscale4,
    const float* __restrict__ target, float* __restrict__ ws)
{
    __shared__ float redK[8];        // KL cross-wave partials
    __shared__ int   redR[4][16];    // rank cross-wave: [wave][lt0..7, eq0..7]
    __shared__ int   tot[16];        // block totals: lt[8], eq[8]
    __shared__ int   tieoff[8];

    const int tid = threadIdx.x, bid = blockIdx.x;
    const int lane = tid & 63, w = tid >> 6;

    if (bid == 0 && tid == 0) ((int*)ws)[WS_CNT] = 0;   // for kernelB's ticket

    const float4* __restrict__ tg4 = (const float4*)target;   // {t,ev,t,ev}

    // ---- 20-deep KL load burst (in-flight bytes = the BW lever) ----
    const int mb = bid * 2048 + tid;          // modality f4 base (2048 f4/block/array)
    const int jb = bid * 512 + tid;           // joint f4 base (512 f4/block/array)
    float4 ml0 = mloc4[mb],        ms0 = mscale4[mb];
    float4 ml1 = mloc4[mb + 256],  ms1 = mscale4[mb + 256];
    float4 ml2 = mloc4[mb + 512],  ms2 = mscale4[mb + 512];
    float4 ml3 = mloc4[mb + 768],  ms3 = mscale4[mb + 768];
    float4 ml4_ = mloc4[mb + 1024], ms4 = mscale4[mb + 1024];
    float4 ml5 = mloc4[mb + 1280], ms5 = mscale4[mb + 1280];
    float4 ml6 = mloc4[mb + 1536], ms6 = mscale4[mb + 1536];
    float4 ml7 = mloc4[mb + 1792], ms7 = mscale4[mb + 1792];
    float4 jl0 = jloc4[jb],        js0 = jscale4[jb];
    float4 jl1 = jloc4[jb + 256],  js1 = jscale4[jb + 256];
    // own times for the 8 rank elements (wave-uniform small loads)
    const float4 tp0 = tg4[4 * bid],     tp1 = tg4[4 * bid + 1];
    const float4 tp2 = tg4[4 * bid + 2], tp3 = tg4[4 * bid + 3];

    // ---- KL compute (burst drains; regs freed for table) ----
    float km = kl4(ml0, ms0) + kl4(ml1, ms1) + kl4(ml2, ms2) + kl4(ml3, ms3)
             + kl4(ml4_, ms4) + kl4(ml5, ms5) + kl4(ml6, ms6) + kl4(ml7, ms7);
    float kj = kl4(jl0, js0) + kl4(jl1, js1);

    // issue table batch-1 while the waveSum chains run
    const int st = bid & 15;                  // per-block stagger of table sweep
    float4 buf[8];
#pragma unroll
    for (int k = 0; k < 8; ++k) buf[k] = tg4[tid + 256 * ((k + st) & 15)];

    km = waveSum(km);
    kj = waveSum(kj);
    if (lane == 0) { redK[w] = km; redK[4 + w] = kj; }

    // ---- rank: compares vs 8 element-times ----
    float te[8];
    te[0] = tp0.x; te[1] = tp0.z; te[2] = tp1.x; te[3] = tp1.z;
    te[4] = tp2.x; te[5] = tp2.z; te[6] = tp3.x; te[7] = tp3.z;
    int lt[8] = {0,0,0,0,0,0,0,0}, eq[8] = {0,0,0,0,0,0,0,0};

#pragma unroll
    for (int k = 0; k < 8; ++k) {
        const float4 f = buf[k];
#pragma unroll
        for (int e = 0; e < 8; ++e) {
            lt[e] += (f.x <  te[e]) ? 1 : 0;
            lt[e] += (f.z <  te[e]) ? 1 : 0;
            eq[e] += (f.x == te[e]) ? 1 : 0;
            eq[e] += (f.z == te[e]) ? 1 : 0;
        }
    }
#pragma unroll
    for (int k = 0; k < 8; ++k) buf[k] = tg4[tid + 256 * ((k + 8 + st) & 15)];
#pragma unroll
    for (int k = 0; k < 8; ++k) {
        const float4 f = buf[k];
#pragma unroll
        for (int e = 0; e < 8; ++e) {
            lt[e] += (f.x <  te[e]) ? 1 : 0;
            lt[e] += (f.z <  te[e]) ? 1 : 0;
            eq[e] += (f.x == te[e]) ? 1 : 0;
            eq[e] += (f.z == te[e]) ? 1 : 0;
        }
    }

#pragma unroll
    for (int e = 0; e < 8; ++e) { lt[e] = waveSumI(lt[e]); eq[e] = waveSumI(eq[e]); }
    if (lane == 0) {
#pragma unroll
        for (int e = 0; e < 8; ++e) { redR[w][e] = lt[e]; redR[w][8 + e] = eq[e]; }
    }
    __syncthreads();

    if (tid < 16) tot[tid] = redR[0][tid] + redR[1][tid] + redR[2][tid] + redR[3][tid];
    if (tid < 8)  tieoff[tid] = 0;
    if (tid == 16) ws[WS_KM + bid]        = redK[0] + redK[1] + redK[2] + redK[3];
    if (tid == 17) ws[WS_KM + 1024 + bid] = redK[4] + redK[5] + redK[6] + redK[7];
    __syncthreads();

    // rare, block-uniform tie handling: stable offset among equal times
    bool tie = false;
#pragma unroll
    for (int e = 0; e < 8; ++e) tie = tie || (tot[8 + e] > 1);
    if (tie) {
        int ql[8] = {0,0,0,0,0,0,0,0};
        for (int k = 0; k < 16; ++k) {
            const float4 f = tg4[tid + 256 * k];      // L2-hot rescan
            const int j = (tid + 256 * k) * 2;
#pragma unroll
            for (int e = 0; e < 8; ++e) {
                const int ee = bid * 8 + e;
                ql[e] += (f.x == te[e] && j     < ee) ? 1 : 0;
                ql[e] += (f.z == te[e] && j + 1 < ee) ? 1 : 0;
            }
        }
#pragma unroll
        for (int e = 0; e < 8; ++e) ql[e] = waveSumI(ql[e]);
        if (lane == 0) {
#pragma unroll
            for (int e = 0; e < 8; ++e) redR[w][e] = ql[e];
        }
        __syncthreads();
        if (tid < 8) tieoff[tid] = redR[0][tid] + redR[1][tid] + redR[2][tid] + redR[3][tid];
        __syncthreads();
    }

    // scatter: 40 plain stores (5 streams x 8 elems) + 8 rank stores
    if (tid < 40) {
        const int e = tid / 5, s = tid % 5;
        const int ee = bid * 8 + e;
        const int slot = tot[e] + tieoff[e];          // bijection 0..N-1 even with ties
        const float h = (s == 0) ? jlh[ee] : mlh[(s - 1) * N + ee];
        ws[WS_SE + s * N + slot] = __expf(h);
    } else if (tid < 48) {
        const int e = tid - 40;
        ((int*)ws)[WS_RANK + bid * 8 + e] = tot[e];
    }
}

// ---- kernel B: 5 parallel stream blocks (scan + gather + KM duty) + last-block combine ----
__global__ __launch_bounds__(1024) void kernelB(
    const float* __restrict__ jlh, const float* __restrict__ mlh,
    const float* __restrict__ target, const float* __restrict__ alpha_p,
    const float* __restrict__ beta_p, float* __restrict__ ws,
    float* __restrict__ out)
{
    __shared__ float suf[N];         // 32 KB suffix table for this block's stream
    __shared__ float wt[16];
    __shared__ float red[16][3];
    __shared__ int tk;

    const int tid = threadIdx.x, s = blockIdx.x;     // s = stream 0..4
    const int lane = tid & 63, w = tid >> 6;

    // ---- load this stream's sortedE slice + hierarchical suffix scan ----
    const float4* __restrict__ se4 = (const float4*)(ws + WS_SE + s * N);
    const float4 a = se4[tid * 2], b = se4[tid * 2 + 1];
    float v[8];
    v[0] = a.x; v[1] = a.y; v[2] = a.z; v[3] = a.w;
    v[4] = b.x; v[5] = b.y; v[6] = b.z; v[7] = b.w;
#pragma unroll
    for (int k = 6; k >= 0; --k) v[k] += v[k + 1];
    const float T = v[0];
    float x = T;                     // wave-level inclusive suffix of thread totals
#pragma unroll
    for (int off = 1; off < 64; off <<= 1) {
        const float y = __shfl_down(x, off, 64);
        if (lane + off < 64) x += y;
    }
    if (lane == 0) wt[w] = x;        // wave totals
    __syncthreads();
    float offw = 0.f;
    for (int ww = w + 1; ww < 16; ++ww) offw += wt[ww];
    const float excl = offw + (x - T);
#pragma unroll
    for (int k = 0; k < 8; ++k) suf[tid * 8 + k] = excl + v[k];
    __syncthreads();

    // ---- gather + cox partial for this stream (8 contiguous elements/thread) ----
    const float4* __restrict__ tg4 = (const float4*)target;
    const float4 p0 = tg4[tid * 4], p1 = tg4[tid * 4 + 1];
    const float4 p2 = tg4[tid * 4 + 2], p3 = tg4[tid * 4 + 3];
    const int4* __restrict__ rk4 = (const int4*)((const int*)ws + WS_RANK);
    const int4 r0 = rk4[tid * 2], r1 = rk4[tid * 2 + 1];
    const float4* __restrict__ hsrc =
        (s == 0) ? (const float4*)jlh : (const float4*)(mlh + (s - 1) * N);
    const float4 h0 = hsrc[tid * 2], h1 = hsrc[tid * 2 + 1];

    const float ev[8] = {p0.y, p0.w, p1.y, p1.w, p2.y, p2.w, p3.y, p3.w};
    const int   rk[8] = {r0.x, r0.y, r0.z, r0.w, r1.x, r1.y, r1.z, r1.w};
    const float hh[8] = {h0.x, h0.y, h0.z, h0.w, h1.x, h1.y, h1.z, h1.w};

    float cs = 0.f, evs = 0.f;
#pragma unroll
    for (int k = 0; k < 8; ++k) {
        cs += ev[k] * (hh[k] - __logf(suf[rk[k]]));
        evs += ev[k];
    }

    // ---- extra duty (parallel with other blocks): KM pre-combine ----
    float extra = 0.f;
    if (s == 1)      extra = ws[WS_KM + tid];         // modality partials (1024)
    else if (s == 2) extra = ws[WS_KM + 1024 + tid];  // joint partials (1024)
    if (tid >= 1024) extra = 0.f;                     // (defensive; blockDim==1024)

    cs = waveSum(cs); evs = waveSum(evs); extra = waveSum(extra);
    if (lane == 0) { red[w][0] = cs; red[w][1] = evs; red[w][2] = extra; }
    __syncthreads();

    if (tid == 0) {
        float c = 0.f, e = 0.f, xx = 0.f;
        for (int ww = 0; ww < 16; ++ww) { c += red[ww][0]; e += red[ww][1]; xx += red[ww][2]; }
        __hip_atomic_store(&ws[WS_FIN + s], c, __ATOMIC_RELEASE, __HIP_MEMORY_SCOPE_AGENT);
        if (s == 0)
            __hip_atomic_store(&ws[WS_FIN + 5], e, __ATOMIC_RELEASE, __HIP_MEMORY_SCOPE_AGENT);
        if (s == 1)
            __hip_atomic_store(&ws[WS_FIN + 6], xx, __ATOMIC_RELEASE, __HIP_MEMORY_SCOPE_AGENT);
        if (s == 2)
            __hip_atomic_store(&ws[WS_FIN + 7], xx, __ATOMIC_RELEASE, __HIP_MEMORY_SCOPE_AGENT);
        tk = __hip_atomic_fetch_add((int*)ws + WS_CNT, 1,
                                    __ATOMIC_ACQ_REL, __HIP_MEMORY_SCOPE_AGENT);
    }
    __syncthreads();

    if (tk == 4 && tid == 0) {       // last-finishing block: 8 scalar loads + arithmetic
        float c[8];
#pragma unroll
        for (int q = 0; q < 8; ++q)
            c[q] = __hip_atomic_load(&ws[WS_FIN + q],
                                     __ATOMIC_RELAXED, __HIP_MEMORY_SCOPE_AGENT);
        const float EV = c[5];
        const float alpha = alpha_p[0], beta = beta_p[0];
        const float cox_j = -c[0] / EV;
        const float cox_m = -(c[1] + c[2] + c[3] + c[4]) / EV;
        out[0] = cox_j + beta * (c[7] / (float)N) + alpha * (cox_m + beta * (c[6] / (float)N));
    }
}

extern "C" void kernel_launch(void* const* d_in, const int* in_sizes, int n_in,
                              void* d_out, int out_size, void* d_ws, size_t ws_size,
                              hipStream_t stream) {
    const float* jlh    = (const float*)d_in[0];  // (N,)
    const float* mlh    = (const float*)d_in[1];  // (M,N)
    const float* jloc   = (const float*)d_in[2];  // (N,L)
    const float* jscale = (const float*)d_in[3];  // (N,L)
    const float* mloc   = (const float*)d_in[4];  // (M,N,L)
    const float* mscale = (const float*)d_in[5];  // (M,N,L)
    const float* target = (const float*)d_in[6];  // (N,2)
    const float* alpha  = (const float*)d_in[7];
    const float* beta   = (const float*)d_in[8];
    float* out = (float*)d_out;
    float* ws  = (float*)d_ws;

    kernelA<<<GRID_A, 256, 0, stream>>>(
        jlh, mlh, (const float4*)jloc, (const float4*)jscale,
        (const float4*)mloc, (const float4*)mscale, target, ws);
    kernelB<<<5, 1024, 0, stream>>>(jlh, mlh, target, alpha, beta, ws, out);
}